// Round 6
// baseline (1184.625 us; speedup 1.0000x reference)
//
#include <hip/hip_runtime.h>
#include <math.h>

#define NTHREADS 512
#define TOUT 252            // outputs per block
#define NP 256              // x2/t3/x4 positions, base P0-1
#define X1ROWS 260          // x1 positions, base P0-3
#define X1S 40              // x1T row stride (ushorts): cols 0..19 data, 20..31 zero
#define X2S 40              // x2T stride: 40 real channels
#define T3S 80              // t3T stride: 80 real channels
#define X4S 40              // x4T stride: 40 real channels (rows 258)
#define X5S 24              // x5T stride: 20 real channels
#define NDIF 264            // dif, base P0-5
#define NUU 266             // uu, base J0-4

typedef unsigned short u16;
typedef unsigned int u32;
typedef __attribute__((ext_vector_type(8))) short bf16x8;   // 8 bf16 = 4 VGPR
typedef __attribute__((ext_vector_type(4))) float f32x4;    // MFMA acc

__device__ __forceinline__ float elu_f(float x) {
    return x > 0.0f ? x : (__expf(x) - 1.0f);
}
__device__ __forceinline__ float sq_f(float x) { return x * x; }
__device__ __forceinline__ u16 f2bf(float f) {
    union { float f; u32 u; } v; v.f = f;
    u32 r = v.u + 0x7FFFu + ((v.u >> 16) & 1u);   // RNE
    return (u16)(r >> 16);
}
__device__ __forceinline__ float bf2f(u16 h) {
    union { u32 u; float f; } v; v.u = ((u32)h) << 16;
    return v.f;
}
__device__ __forceinline__ void pack8(const float* v, bf16x8& a) {
    #pragma unroll
    for (int j = 0; j < 8; ++j) a[j] = (short)f2bf(v[j]);
}
__device__ __forceinline__ bf16x8 zero_frag() {
    bf16x8 z;
    #pragma unroll
    for (int j = 0; j < 8; ++j) z[j] = 0;
    return z;
}

// NOTE: (512,1) not (512,4) — the 4-waves/EU floor capped VGPRs at 64 and
// spilled ~500 MB/dispatch to scratch (R5: WRITE_SIZE 507 MB, VGPR_Count 64).
__global__ __launch_bounds__(NTHREADS, 1) void weno_nn_kernel(
    const float* __restrict__ uu, const float* __restrict__ e_ptr,
    const float* __restrict__ w1, const float* __restrict__ b1,
    const float* __restrict__ w2, const float* __restrict__ b2,
    const float* __restrict__ w3, const float* __restrict__ b3,
    const float* __restrict__ w4, const float* __restrict__ b4,
    const float* __restrict__ w5, const float* __restrict__ b5,
    const float* __restrict__ w6, const float* __restrict__ b6,
    float* __restrict__ out, int n_out, int N)
{
    __shared__ float s_uu[NUU];
    __shared__ float s_dif[NDIF];                       // reused as beta later
    __shared__ __align__(16) u16 bufA[NP * T3S];        // x1T(260x40) -> t3T(256x80) -> x5T(256x24)
    __shared__ __align__(16) u16 bufB[258 * X4S];       // x2T(256x40) -> x4T(258x40)

    const int tid  = threadIdx.x;
    const int lane = tid & 63;
    const int wv_id = __builtin_amdgcn_readfirstlane(tid >> 6);  // 0..7
    const int m    = lane & 15;         // M/N index within frag
    const int q    = lane >> 4;         // quad, 0..3
    const int J0   = blockIdx.x * TOUT;
    const int P0   = J0 + 2;
    const int U0   = J0 - 4;

    // ================= stage 0: uu tile =================
    for (int i = tid; i < NUU; i += NTHREADS) {
        int g = U0 + i;
        s_uu[i] = (g >= 0 && g < N) ? uu[g] : 0.0f;
    }
    __syncthreads();

    // ================= avg-diff =================
    for (int d = tid; d < NDIF; d += NTHREADS) {
        int g = P0 - 5 + d;
        float v = 0.0f;
        if (g >= 0 && g < N) {
            int j1 = g < N - 2 ? g : N - 2;
            int j0 = g - 1 > 0 ? g - 1 : 0;
            float dl = s_uu[j1 + 1 - U0] - s_uu[j1 - U0];
            float dr = s_uu[j0 + 1 - U0] - s_uu[j0 - U0];
            v = 0.5f * (dl + dr);
        }
        s_dif[d] = v;
    }
    __syncthreads();

    // ================= conv1: 1->20, k=5, elu -> x1T[pos][ic] =================
    for (int s = tid; s < X1ROWS; s += NTHREADS) {
        int g = P0 - 3 + s;
        bool valid = (g >= 0 && g < N);
        float dv[5];
        #pragma unroll
        for (int k = 0; k < 5; ++k) dv[k] = s_dif[s + k];
        float v[20];
        #pragma unroll
        for (int oc = 0; oc < 20; ++oc) {
            float a = b1[oc];
            #pragma unroll
            for (int k = 0; k < 5; ++k) a += w1[oc * 5 + k] * dv[k];
            v[oc] = valid ? elu_f(a) : 0.0f;
        }
        u32* rp = (u32*)&bufA[s * X1S];
        #pragma unroll
        for (int p = 0; p < 10; ++p)
            rp[p] = (u32)f2bf(v[2 * p]) | ((u32)f2bf(v[2 * p + 1]) << 16);
        #pragma unroll
        for (int p = 10; p < 16; ++p) rp[p] = 0;     // zero-pad ic 20..31
    }
    __syncthreads();

    // ================= conv2: 20->40, k=5 (im2col K=160: k=dk*32+ic) =================
    {
        // A-frags: [3 M-tiles][5 K-steps]
        bf16x8 a2[3][5];
        #pragma unroll
        for (int mt = 0; mt < 3; ++mt) {
            int oc = mt * 16 + m;
            #pragma unroll
            for (int s = 0; s < 5; ++s) {
                float wvv[8];
                #pragma unroll
                for (int j = 0; j < 8; ++j) {
                    int ic = q * 8 + j;
                    wvv[j] = (oc < 40 && ic < 20) ? w2[oc * 100 + ic * 5 + s] : 0.0f;
                }
                pack8(wvv, a2[mt][s]);
            }
        }
        float bias2[3][4];
        #pragma unroll
        for (int mt = 0; mt < 3; ++mt) {
            #pragma unroll
            for (int r = 0; r < 4; ++r) {
                int oc = mt * 16 + 4 * q + r;
                bias2[mt][r] = (oc < 40) ? b2[oc] : 0.0f;
            }
        }
        for (int t = 0; t < 2; ++t) {
            const int N0 = (wv_id * 2 + t) * 16;
            f32x4 acc[3];
            #pragma unroll
            for (int mt = 0; mt < 3; ++mt) {
                #pragma unroll
                for (int r = 0; r < 4; ++r) acc[mt][r] = 0.0f;
            }
            #pragma unroll
            for (int s = 0; s < 5; ++s) {
                bf16x8 bfrag = *(const bf16x8*)&bufA[(N0 + m + s) * X1S + q * 8];
                #pragma unroll
                for (int mt = 0; mt < 3; ++mt)
                    acc[mt] = __builtin_amdgcn_mfma_f32_16x16x32_bf16(a2[mt][s], bfrag, acc[mt], 0, 0, 0);
            }
            #pragma unroll
            for (int mt = 0; mt < 3; ++mt) {
                int oc0 = mt * 16 + 4 * q;
                if (oc0 < 40) {
                    u32 pk0 = (u32)f2bf(elu_f(acc[mt][0] + bias2[mt][0])) |
                              ((u32)f2bf(elu_f(acc[mt][1] + bias2[mt][1])) << 16);
                    u32 pk1 = (u32)f2bf(elu_f(acc[mt][2] + bias2[mt][2])) |
                              ((u32)f2bf(elu_f(acc[mt][3] + bias2[mt][3])) << 16);
                    u32* wp = (u32*)&bufB[(N0 + m) * X2S + oc0];
                    wp[0] = pk0; wp[1] = pk1;
                }
            }
        }
    }
    __syncthreads();

    // ================= conv3: 40->80, k=1 (K=40 pad 64) =================
    {
        bf16x8 a3[5][2];
        #pragma unroll
        for (int mt = 0; mt < 5; ++mt) {
            int oc = mt * 16 + m;
            #pragma unroll
            for (int s = 0; s < 2; ++s) {
                float wvv[8];
                #pragma unroll
                for (int j = 0; j < 8; ++j) {
                    int k = s * 32 + q * 8 + j;
                    wvv[j] = (k < 40) ? w3[oc * 40 + k] : 0.0f;
                }
                pack8(wvv, a3[mt][s]);
            }
        }
        float bias3[5][4];
        #pragma unroll
        for (int mt = 0; mt < 5; ++mt) {
            #pragma unroll
            for (int r = 0; r < 4; ++r) bias3[mt][r] = b3[mt * 16 + 4 * q + r];
        }
        for (int t = 0; t < 2; ++t) {
            const int N0 = (wv_id * 2 + t) * 16;
            f32x4 acc[5];
            #pragma unroll
            for (int mt = 0; mt < 5; ++mt) {
                #pragma unroll
                for (int r = 0; r < 4; ++r) acc[mt][r] = 0.0f;
            }
            // s=0: k 0..31
            {
                bf16x8 bfrag = *(const bf16x8*)&bufB[(N0 + m) * X2S + q * 8];
                #pragma unroll
                for (int mt = 0; mt < 5; ++mt)
                    acc[mt] = __builtin_amdgcn_mfma_f32_16x16x32_bf16(a3[mt][0], bfrag, acc[mt], 0, 0, 0);
            }
            // s=1: only q==0 has valid k (32..39)
            {
                bf16x8 bfrag = zero_frag();
                if (q == 0) bfrag = *(const bf16x8*)&bufB[(N0 + m) * X2S + 32];
                #pragma unroll
                for (int mt = 0; mt < 5; ++mt)
                    acc[mt] = __builtin_amdgcn_mfma_f32_16x16x32_bf16(a3[mt][1], bfrag, acc[mt], 0, 0, 0);
            }
            #pragma unroll
            for (int mt = 0; mt < 5; ++mt) {
                int oc0 = mt * 16 + 4 * q;
                u32 pk0 = (u32)f2bf(elu_f(acc[mt][0] + bias3[mt][0])) |
                          ((u32)f2bf(elu_f(acc[mt][1] + bias3[mt][1])) << 16);
                u32 pk1 = (u32)f2bf(elu_f(acc[mt][2] + bias3[mt][2])) |
                          ((u32)f2bf(elu_f(acc[mt][3] + bias3[mt][3])) << 16);
                u32* wp = (u32*)&bufA[(N0 + m) * T3S + oc0];
                wp[0] = pk0; wp[1] = pk1;
            }
        }
    }
    __syncthreads();

    // ================= conv4: 80->40, k=1 (K=80 pad 96) =================
    {
        bf16x8 a4[3][3];
        #pragma unroll
        for (int mt = 0; mt < 3; ++mt) {
            int oc = mt * 16 + m;
            #pragma unroll
            for (int s = 0; s < 3; ++s) {
                float wvv[8];
                #pragma unroll
                for (int j = 0; j < 8; ++j) {
                    int k = s * 32 + q * 8 + j;
                    wvv[j] = (oc < 40 && k < 80) ? w4[oc * 80 + k] : 0.0f;
                }
                pack8(wvv, a4[mt][s]);
            }
        }
        float bias4[3][4];
        #pragma unroll
        for (int mt = 0; mt < 3; ++mt) {
            #pragma unroll
            for (int r = 0; r < 4; ++r) {
                int oc = mt * 16 + 4 * q + r;
                bias4[mt][r] = (oc < 40) ? b4[oc] : 0.0f;
            }
        }
        // zero-pad x4T rows 256,257 (read by conv5 at right edge of tile)
        if (tid < 80) bufB[256 * X4S + tid] = 0;
        for (int t = 0; t < 2; ++t) {
            const int N0 = (wv_id * 2 + t) * 16;
            f32x4 acc[3];
            #pragma unroll
            for (int mt = 0; mt < 3; ++mt) {
                #pragma unroll
                for (int r = 0; r < 4; ++r) acc[mt][r] = 0.0f;
            }
            #pragma unroll
            for (int s = 0; s < 3; ++s) {
                int k0 = s * 32 + q * 8;
                bf16x8 bfrag = zero_frag();
                if (k0 < 80) bfrag = *(const bf16x8*)&bufA[(N0 + m) * T3S + k0];
                #pragma unroll
                for (int mt = 0; mt < 3; ++mt)
                    acc[mt] = __builtin_amdgcn_mfma_f32_16x16x32_bf16(a4[mt][s], bfrag, acc[mt], 0, 0, 0);
            }
            #pragma unroll
            for (int mt = 0; mt < 3; ++mt) {
                int oc0 = mt * 16 + 4 * q;
                if (oc0 < 40) {
                    u32 pk0 = (u32)f2bf(elu_f(acc[mt][0] + bias4[mt][0])) |
                              ((u32)f2bf(elu_f(acc[mt][1] + bias4[mt][1])) << 16);
                    u32 pk1 = (u32)f2bf(elu_f(acc[mt][2] + bias4[mt][2])) |
                              ((u32)f2bf(elu_f(acc[mt][3] + bias4[mt][3])) << 16);
                    u32* wp = (u32*)&bufB[(N0 + m) * X4S + oc0];
                    wp[0] = pk0; wp[1] = pk1;
                }
            }
        }
    }
    __syncthreads();

    // ================= conv5: 40->20, k=3 (im2col K=120: k=dk*40+ic) =================
    {
        bf16x8 a5[2][4];
        #pragma unroll
        for (int mt = 0; mt < 2; ++mt) {
            int oc = mt * 16 + m;
            #pragma unroll
            for (int s = 0; s < 4; ++s) {
                int k0 = s * 32 + q * 8;
                int dk = k0 / 40, ic0 = k0 - dk * 40;
                float wvv[8];
                #pragma unroll
                for (int j = 0; j < 8; ++j)
                    wvv[j] = (oc < 20 && k0 < 120) ? w5[oc * 120 + (ic0 + j) * 3 + dk] : 0.0f;
                pack8(wvv, a5[mt][s]);
            }
        }
        float bias5[2][4];
        #pragma unroll
        for (int mt = 0; mt < 2; ++mt) {
            #pragma unroll
            for (int r = 0; r < 4; ++r) {
                int oc = mt * 16 + 4 * q + r;
                bias5[mt][r] = (oc < 20) ? b5[oc] : 0.0f;
            }
        }
        for (int t = 0; t < 2; ++t) {
            const int N0 = (wv_id * 2 + t) * 16;
            f32x4 acc[2];
            #pragma unroll
            for (int mt = 0; mt < 2; ++mt) {
                #pragma unroll
                for (int r = 0; r < 4; ++r) acc[mt][r] = 0.0f;
            }
            #pragma unroll
            for (int s = 0; s < 4; ++s) {
                int k0 = s * 32 + q * 8;
                bf16x8 bfrag = zero_frag();
                if (k0 < 120) {
                    int dk = k0 / 40, ic0 = k0 - dk * 40;
                    bfrag = *(const bf16x8*)&bufB[(N0 + m + dk) * X4S + ic0];
                }
                #pragma unroll
                for (int mt = 0; mt < 2; ++mt)
                    acc[mt] = __builtin_amdgcn_mfma_f32_16x16x32_bf16(a5[mt][s], bfrag, acc[mt], 0, 0, 0);
            }
            #pragma unroll
            for (int mt = 0; mt < 2; ++mt) {
                int oc0 = mt * 16 + 4 * q;
                if (oc0 < 20) {
                    u32 pk0 = (u32)f2bf(elu_f(acc[mt][0] + bias5[mt][0])) |
                              ((u32)f2bf(elu_f(acc[mt][1] + bias5[mt][1])) << 16);
                    u32 pk1 = (u32)f2bf(elu_f(acc[mt][2] + bias5[mt][2])) |
                              ((u32)f2bf(elu_f(acc[mt][3] + bias5[mt][3])) << 16);
                    u32* wp = (u32*)&bufA[(N0 + m) * X5S + oc0];
                    wp[0] = pk0; wp[1] = pk1;
                }
            }
        }
    }
    __syncthreads();

    // ================= conv6: 20->1, sigmoid + 0.1 -> beta (reuse s_dif) =================
    if (tid < 254) {
        float a = b6[0];
        #pragma unroll
        for (int c = 0; c < 20; ++c)
            a += w6[c] * bf2f(bufA[tid * X5S + c]);
        s_dif[tid] = 1.0f / (1.0f + __expf(-a)) + 0.1f;
    }
    __syncthreads();

    // ================= WENO5 =================
    const float eps = e_ptr[0];
    if (tid < TOUT) {
        int j = J0 + tid;
        if (j < n_out) {
            float a  = s_uu[tid + 5];
            float b  = s_uu[tid + 6];
            float c  = s_uu[tid + 7];
            float d  = s_uu[tid + 8];
            float ee = s_uu[tid + 9];
            float f  = s_uu[tid + 10];
            float m0 = s_dif[tid];
            float m1 = s_dif[tid + 1];
            float m2 = s_dif[tid + 2];

            const float i6 = 1.0f / 6.0f;
            float fp0 = (11.f * d - 7.f * ee + 2.f * f) * i6;
            float fp1 = (2.f * c + 5.f * d - ee) * i6;
            float fp2 = (-b + 5.f * c + 2.f * d) * i6;
            float fn0 = (11.f * c - 7.f * d + 2.f * ee) * i6;
            float fn1 = (2.f * b + 5.f * c - d) * i6;
            float fn2 = (-a + 5.f * b + 2.f * c) * i6;

            const float c1312 = 13.f / 12.f;
            float bp0 = c1312 * sq_f(d - 2.f * ee + f) + 0.25f * sq_f(3.f * d - 4.f * ee + f);
            float bp1 = c1312 * sq_f(c - 2.f * d + ee) + 0.25f * sq_f(c - ee);
            float bp2 = c1312 * sq_f(b - 2.f * c + d) + 0.25f * sq_f(b - 4.f * c + 3.f * d);
            float bn0 = c1312 * sq_f(c - 2.f * d + ee) + 0.25f * sq_f(3.f * c - 4.f * d + ee);
            float bn1 = c1312 * sq_f(b - 2.f * c + d) + 0.25f * sq_f(b - d);
            float bn2 = c1312 * sq_f(a - 2.f * b + c) + 0.25f * sq_f(a - 4.f * b + 3.f * c);

            bp0 *= m0; bp1 *= m1; bp2 *= m2;
            bn0 *= m0; bn1 *= m1; bn2 *= m2;

            float q0 = eps + bp0; q0 *= q0;
            float q1 = eps + bp1; q1 *= q1;
            float q2 = eps + bp2; q2 *= q2;
            float brs = bp2 - bp0; brs *= brs;
            float o0 = 0.1f * (1.f + brs / q0);
            float o1 = 0.6f * (1.f + brs / q1);
            float o2 = 0.3f * (1.f + brs / q2);
            float inv = 1.f / (o0 + o1 + o2);
            float fluxp = (o0 * fp0 + o1 * fp1 + o2 * fp2) * inv;

            q0 = eps + bn0; q0 *= q0;
            q1 = eps + bn1; q1 *= q1;
            q2 = eps + bn2; q2 *= q2;
            brs = bn2 - bn0; brs *= brs;
            o0 = 0.1f * (1.f + brs / q0);
            o1 = 0.6f * (1.f + brs / q1);
            o2 = 0.3f * (1.f + brs / q2);
            inv = 1.f / (o0 + o1 + o2);
            float fluxn = (o0 * fn0 + o1 * fn1 + o2 * fn2) * inv;

            out[j] = fluxp - fluxn;
        }
    }
}

extern "C" void kernel_launch(void* const* d_in, const int* in_sizes, int n_in,
                              void* d_out, int out_size, void* d_ws, size_t ws_size,
                              hipStream_t stream) {
    const float* uu = (const float*)d_in[0];
    const float* e  = (const float*)d_in[1];
    const float* w1 = (const float*)d_in[2];
    const float* b1 = (const float*)d_in[3];
    const float* w2 = (const float*)d_in[4];
    const float* b2 = (const float*)d_in[5];
    const float* w3 = (const float*)d_in[6];
    const float* b3 = (const float*)d_in[7];
    const float* w4 = (const float*)d_in[8];
    const float* b4 = (const float*)d_in[9];
    const float* w5 = (const float*)d_in[10];
    const float* b5 = (const float*)d_in[11];
    const float* w6 = (const float*)d_in[12];
    const float* b6 = (const float*)d_in[13];
    float* out = (float*)d_out;
    const int N = in_sizes[0];
    const int nblocks = (out_size + TOUT - 1) / TOUT;
    weno_nn_kernel<<<nblocks, NTHREADS, 0, stream>>>(
        uu, e, w1, b1, w2, b2, w3, b3, w4, b4, w5, b5, w6, b6,
        out, out_size, N);
}

// Round 7
// 315.189 us; speedup vs baseline: 3.7585x; 3.7585x over previous
//
#include <hip/hip_runtime.h>
#include <math.h>

#define NTHREADS 512
#define TOUT 252            // outputs per block
#define NP 256              // x2/t3/x4 positions, base P0-1
#define X1ROWS 260          // x1 positions, base P0-3
#define X1S 40              // x1T row stride (ushorts): cols 0..19 data, 20..31 zero
#define X2S 40              // x2T stride: 40 real channels
#define T3S 80              // t3T stride: 80 real channels
#define X4S 40              // x4T stride: 40 real channels (rows 258)
#define X5S 24              // x5T stride: 20 real channels
#define NDIF 264            // dif, base P0-5
#define NUU 266             // uu, base J0-4

// weight-fragment table in d_ws: 42 frags x 64 lanes x 8 bf16 (16 B)
#define F2_BASE 0           // conv2: 15 frags (mt 0..2, s 0..4)
#define F3_BASE 15          // conv3: 10 frags (mt 0..4, s 0..1)
#define F4_BASE 25          // conv4: 9  frags (mt 0..2, s 0..2)
#define F5_BASE 34          // conv5: 8  frags (mt 0..1, s 0..3)
#define NFRAGS 42

typedef unsigned short u16;
typedef unsigned int u32;
typedef __attribute__((ext_vector_type(8))) short bf16x8;   // 8 bf16 = 4 VGPR
typedef __attribute__((ext_vector_type(4))) float f32x4;    // MFMA acc

__device__ __forceinline__ float elu_f(float x) {
    return x > 0.0f ? x : (__expf(x) - 1.0f);
}
__device__ __forceinline__ float sq_f(float x) { return x * x; }
__device__ __forceinline__ u16 f2bf(float f) {
    union { float f; u32 u; } v; v.f = f;
    u32 r = v.u + 0x7FFFu + ((v.u >> 16) & 1u);   // RNE
    return (u16)(r >> 16);
}
__device__ __forceinline__ float bf2f(u16 h) {
    union { u32 u; float f; } v; v.u = ((u32)h) << 16;
    return v.f;
}

// ---- setup kernel: build all MFMA A-operand weight frags once per launch ----
__global__ __launch_bounds__(64) void build_frags_kernel(
    const float* __restrict__ w2, const float* __restrict__ w3,
    const float* __restrict__ w4, const float* __restrict__ w5,
    u16* __restrict__ ws)
{
    const int f = blockIdx.x;      // 0..41
    const int lane = threadIdx.x;  // 0..63
    const int m = lane & 15;
    const int q = lane >> 4;
    float wvv[8];
    #pragma unroll
    for (int j = 0; j < 8; ++j) wvv[j] = 0.0f;

    if (f < F3_BASE) {                       // conv2: 20->40 k=5, K-dim = dk*32+ic
        int mt = (f - F2_BASE) / 5, s = (f - F2_BASE) % 5;
        int oc = mt * 16 + m;
        #pragma unroll
        for (int j = 0; j < 8; ++j) {
            int ic = q * 8 + j;
            if (oc < 40 && ic < 20) wvv[j] = w2[oc * 100 + ic * 5 + s];
        }
    } else if (f < F4_BASE) {                // conv3: 40->80 k=1, K=40 pad 64
        int mt = (f - F3_BASE) / 2, s = (f - F3_BASE) % 2;
        int oc = mt * 16 + m;
        #pragma unroll
        for (int j = 0; j < 8; ++j) {
            int k = s * 32 + q * 8 + j;
            if (k < 40) wvv[j] = w3[oc * 40 + k];
        }
    } else if (f < F5_BASE) {                // conv4: 80->40 k=1, K=80 pad 96
        int mt = (f - F4_BASE) / 3, s = (f - F4_BASE) % 3;
        int oc = mt * 16 + m;
        #pragma unroll
        for (int j = 0; j < 8; ++j) {
            int k = s * 32 + q * 8 + j;
            if (oc < 40 && k < 80) wvv[j] = w4[oc * 80 + k];
        }
    } else {                                 // conv5: 40->20 k=3, K=120: k=dk*40+ic
        int mt = (f - F5_BASE) / 4, s = (f - F5_BASE) % 4;
        int oc = mt * 16 + m;
        int k0 = s * 32 + q * 8;
        int dk = k0 / 40, ic0 = k0 - dk * 40;
        #pragma unroll
        for (int j = 0; j < 8; ++j) {
            if (oc < 20 && k0 < 120) wvv[j] = w5[oc * 120 + (ic0 + j) * 3 + dk];
        }
    }
    u32 pk[4];
    #pragma unroll
    for (int p = 0; p < 4; ++p)
        pk[p] = (u32)f2bf(wvv[2 * p]) | ((u32)f2bf(wvv[2 * p + 1]) << 16);
    u32* wp = (u32*)&ws[(f * 64 + lane) * 8];
    wp[0] = pk[0]; wp[1] = pk[1]; wp[2] = pk[2]; wp[3] = pk[3];
}

__device__ __forceinline__ bf16x8 ld_frag(const u16* ws, int f, int lane) {
    return *(const bf16x8*)&ws[(f * 64 + lane) * 8];
}

__global__ __launch_bounds__(NTHREADS, 1) void weno_nn_kernel(
    const float* __restrict__ uu, const float* __restrict__ e_ptr,
    const float* __restrict__ w1, const float* __restrict__ b1,
    const float* __restrict__ b2, const float* __restrict__ b3,
    const float* __restrict__ b4, const float* __restrict__ b5,
    const float* __restrict__ w6, const float* __restrict__ b6,
    const u16* __restrict__ wfr,
    float* __restrict__ out, int n_out, int N)
{
    __shared__ float s_uu[NUU];
    __shared__ float s_dif[NDIF];                       // reused as beta later
    __shared__ __align__(16) u16 bufA[NP * T3S];        // x1T(260x40) -> t3T(256x80) -> x5T(256x24)
    __shared__ __align__(16) u16 bufB[258 * X4S];       // x2T(256x40) -> x4T(258x40)

    const int tid  = threadIdx.x;
    const int lane = tid & 63;
    const int wv_id = __builtin_amdgcn_readfirstlane(tid >> 6);  // 0..7
    const int m    = lane & 15;         // M/N index within frag
    const int q    = lane >> 4;         // quad, 0..3
    const int J0   = blockIdx.x * TOUT;
    const int P0   = J0 + 2;
    const int U0   = J0 - 4;

    // ================= stage 0: uu tile =================
    for (int i = tid; i < NUU; i += NTHREADS) {
        int g = U0 + i;
        s_uu[i] = (g >= 0 && g < N) ? uu[g] : 0.0f;
    }
    __syncthreads();

    // ================= avg-diff =================
    for (int d = tid; d < NDIF; d += NTHREADS) {
        int g = P0 - 5 + d;
        float v = 0.0f;
        if (g >= 0 && g < N) {
            int j1 = g < N - 2 ? g : N - 2;
            int j0 = g - 1 > 0 ? g - 1 : 0;
            float dl = s_uu[j1 + 1 - U0] - s_uu[j1 - U0];
            float dr = s_uu[j0 + 1 - U0] - s_uu[j0 - U0];
            v = 0.5f * (dl + dr);
        }
        s_dif[d] = v;
    }
    __syncthreads();

    // ================= conv1: 1->20, k=5, elu -> x1T[pos][ic] =================
    for (int s = tid; s < X1ROWS; s += NTHREADS) {
        int g = P0 - 3 + s;
        bool valid = (g >= 0 && g < N);
        float dv[5];
        #pragma unroll
        for (int k = 0; k < 5; ++k) dv[k] = s_dif[s + k];
        float v[20];
        #pragma unroll
        for (int oc = 0; oc < 20; ++oc) {
            float a = b1[oc];
            #pragma unroll
            for (int k = 0; k < 5; ++k) a += w1[oc * 5 + k] * dv[k];
            v[oc] = valid ? elu_f(a) : 0.0f;
        }
        u32* rp = (u32*)&bufA[s * X1S];
        #pragma unroll
        for (int p = 0; p < 10; ++p)
            rp[p] = (u32)f2bf(v[2 * p]) | ((u32)f2bf(v[2 * p + 1]) << 16);
        #pragma unroll
        for (int p = 10; p < 16; ++p) rp[p] = 0;     // zero-pad ic 20..31
    }
    __syncthreads();

    // ================= conv2: 20->40, k=5 (im2col K=160) =================
    {
        bf16x8 a2[3][5];
        #pragma unroll
        for (int mt = 0; mt < 3; ++mt)
            #pragma unroll
            for (int s = 0; s < 5; ++s)
                a2[mt][s] = ld_frag(wfr, F2_BASE + mt * 5 + s, lane);
        float bias2[3][4];
        #pragma unroll
        for (int mt = 0; mt < 3; ++mt) {
            #pragma unroll
            for (int r = 0; r < 4; ++r) {
                int oc = mt * 16 + 4 * q + r;
                bias2[mt][r] = (oc < 40) ? b2[oc] : 0.0f;
            }
        }
        for (int t = 0; t < 2; ++t) {
            const int N0 = (wv_id * 2 + t) * 16;
            f32x4 acc[3];
            #pragma unroll
            for (int mt = 0; mt < 3; ++mt) {
                #pragma unroll
                for (int r = 0; r < 4; ++r) acc[mt][r] = 0.0f;
            }
            #pragma unroll
            for (int s = 0; s < 5; ++s) {
                bf16x8 bfrag = *(const bf16x8*)&bufA[(N0 + m + s) * X1S + q * 8];
                #pragma unroll
                for (int mt = 0; mt < 3; ++mt)
                    acc[mt] = __builtin_amdgcn_mfma_f32_16x16x32_bf16(a2[mt][s], bfrag, acc[mt], 0, 0, 0);
            }
            #pragma unroll
            for (int mt = 0; mt < 3; ++mt) {
                int oc0 = mt * 16 + 4 * q;
                if (oc0 < 40) {
                    u32 pk0 = (u32)f2bf(elu_f(acc[mt][0] + bias2[mt][0])) |
                              ((u32)f2bf(elu_f(acc[mt][1] + bias2[mt][1])) << 16);
                    u32 pk1 = (u32)f2bf(elu_f(acc[mt][2] + bias2[mt][2])) |
                              ((u32)f2bf(elu_f(acc[mt][3] + bias2[mt][3])) << 16);
                    u32* wp = (u32*)&bufB[(N0 + m) * X2S + oc0];
                    wp[0] = pk0; wp[1] = pk1;
                }
            }
        }
    }
    __syncthreads();

    // ================= conv3: 40->80, k=1 (K=40 pad 64) =================
    {
        bf16x8 a3[5][2];
        #pragma unroll
        for (int mt = 0; mt < 5; ++mt)
            #pragma unroll
            for (int s = 0; s < 2; ++s)
                a3[mt][s] = ld_frag(wfr, F3_BASE + mt * 2 + s, lane);
        float bias3[5][4];
        #pragma unroll
        for (int mt = 0; mt < 5; ++mt) {
            #pragma unroll
            for (int r = 0; r < 4; ++r) bias3[mt][r] = b3[mt * 16 + 4 * q + r];
        }
        for (int t = 0; t < 2; ++t) {
            const int N0 = (wv_id * 2 + t) * 16;
            f32x4 acc[5];
            #pragma unroll
            for (int mt = 0; mt < 5; ++mt) {
                #pragma unroll
                for (int r = 0; r < 4; ++r) acc[mt][r] = 0.0f;
            }
            // s=0: k 0..31
            {
                bf16x8 bfrag = *(const bf16x8*)&bufB[(N0 + m) * X2S + q * 8];
                #pragma unroll
                for (int mt = 0; mt < 5; ++mt)
                    acc[mt] = __builtin_amdgcn_mfma_f32_16x16x32_bf16(a3[mt][0], bfrag, acc[mt], 0, 0, 0);
            }
            // s=1: only q==0 has valid k (32..39); other quads multiply zero A-weights
            {
                bf16x8 bfrag = *(const bf16x8*)&bufB[(N0 + m) * X2S + ((q == 0) ? 32 : 0)];
                #pragma unroll
                for (int mt = 0; mt < 5; ++mt)
                    acc[mt] = __builtin_amdgcn_mfma_f32_16x16x32_bf16(a3[mt][1], bfrag, acc[mt], 0, 0, 0);
            }
            #pragma unroll
            for (int mt = 0; mt < 5; ++mt) {
                int oc0 = mt * 16 + 4 * q;
                u32 pk0 = (u32)f2bf(elu_f(acc[mt][0] + bias3[mt][0])) |
                          ((u32)f2bf(elu_f(acc[mt][1] + bias3[mt][1])) << 16);
                u32 pk1 = (u32)f2bf(elu_f(acc[mt][2] + bias3[mt][2])) |
                          ((u32)f2bf(elu_f(acc[mt][3] + bias3[mt][3])) << 16);
                u32* wp = (u32*)&bufA[(N0 + m) * T3S + oc0];
                wp[0] = pk0; wp[1] = pk1;
            }
        }
    }
    __syncthreads();

    // ================= conv4: 80->40, k=1 (K=80 pad 96) =================
    {
        bf16x8 a4[3][3];
        #pragma unroll
        for (int mt = 0; mt < 3; ++mt)
            #pragma unroll
            for (int s = 0; s < 3; ++s)
                a4[mt][s] = ld_frag(wfr, F4_BASE + mt * 3 + s, lane);
        float bias4[3][4];
        #pragma unroll
        for (int mt = 0; mt < 3; ++mt) {
            #pragma unroll
            for (int r = 0; r < 4; ++r) {
                int oc = mt * 16 + 4 * q + r;
                bias4[mt][r] = (oc < 40) ? b4[oc] : 0.0f;
            }
        }
        // zero-pad x4T rows 256,257 (read by conv5 at right edge of tile)
        if (tid < 80) bufB[256 * X4S + tid] = 0;
        for (int t = 0; t < 2; ++t) {
            const int N0 = (wv_id * 2 + t) * 16;
            f32x4 acc[3];
            #pragma unroll
            for (int mt = 0; mt < 3; ++mt) {
                #pragma unroll
                for (int r = 0; r < 4; ++r) acc[mt][r] = 0.0f;
            }
            #pragma unroll
            for (int s = 0; s < 3; ++s) {
                int k0 = s * 32 + q * 8;
                // k0 >= 80 lanes have zero A-weights; clamp address
                bf16x8 bfrag = *(const bf16x8*)&bufA[(N0 + m) * T3S + ((k0 < 80) ? k0 : 0)];
                #pragma unroll
                for (int mt = 0; mt < 3; ++mt)
                    acc[mt] = __builtin_amdgcn_mfma_f32_16x16x32_bf16(a4[mt][s], bfrag, acc[mt], 0, 0, 0);
            }
            #pragma unroll
            for (int mt = 0; mt < 3; ++mt) {
                int oc0 = mt * 16 + 4 * q;
                if (oc0 < 40) {
                    u32 pk0 = (u32)f2bf(elu_f(acc[mt][0] + bias4[mt][0])) |
                              ((u32)f2bf(elu_f(acc[mt][1] + bias4[mt][1])) << 16);
                    u32 pk1 = (u32)f2bf(elu_f(acc[mt][2] + bias4[mt][2])) |
                              ((u32)f2bf(elu_f(acc[mt][3] + bias4[mt][3])) << 16);
                    u32* wp = (u32*)&bufB[(N0 + m) * X4S + oc0];
                    wp[0] = pk0; wp[1] = pk1;
                }
            }
        }
    }
    __syncthreads();

    // ================= conv5: 40->20, k=3 (im2col K=120) =================
    {
        bf16x8 a5[2][4];
        #pragma unroll
        for (int mt = 0; mt < 2; ++mt)
            #pragma unroll
            for (int s = 0; s < 4; ++s)
                a5[mt][s] = ld_frag(wfr, F5_BASE + mt * 4 + s, lane);
        float bias5[2][4];
        #pragma unroll
        for (int mt = 0; mt < 2; ++mt) {
            #pragma unroll
            for (int r = 0; r < 4; ++r) {
                int oc = mt * 16 + 4 * q + r;
                bias5[mt][r] = (oc < 20) ? b5[oc] : 0.0f;
            }
        }
        for (int t = 0; t < 2; ++t) {
            const int N0 = (wv_id * 2 + t) * 16;
            f32x4 acc[2];
            #pragma unroll
            for (int mt = 0; mt < 2; ++mt) {
                #pragma unroll
                for (int r = 0; r < 4; ++r) acc[mt][r] = 0.0f;
            }
            #pragma unroll
            for (int s = 0; s < 4; ++s) {
                int k0 = s * 32 + q * 8;
                int dk = (k0 < 120) ? (k0 / 40) : 0;
                int ic0 = (k0 < 120) ? (k0 - dk * 40) : 0;
                bf16x8 bfrag = *(const bf16x8*)&bufB[(N0 + m + dk) * X4S + ic0];
                #pragma unroll
                for (int mt = 0; mt < 2; ++mt)
                    acc[mt] = __builtin_amdgcn_mfma_f32_16x16x32_bf16(a5[mt][s], bfrag, acc[mt], 0, 0, 0);
            }
            #pragma unroll
            for (int mt = 0; mt < 2; ++mt) {
                int oc0 = mt * 16 + 4 * q;
                if (oc0 < 20) {
                    u32 pk0 = (u32)f2bf(elu_f(acc[mt][0] + bias5[mt][0])) |
                              ((u32)f2bf(elu_f(acc[mt][1] + bias5[mt][1])) << 16);
                    u32 pk1 = (u32)f2bf(elu_f(acc[mt][2] + bias5[mt][2])) |
                              ((u32)f2bf(elu_f(acc[mt][3] + bias5[mt][3])) << 16);
                    u32* wp = (u32*)&bufA[(N0 + m) * X5S + oc0];
                    wp[0] = pk0; wp[1] = pk1;
                }
            }
        }
    }
    __syncthreads();

    // ================= conv6: 20->1, sigmoid + 0.1 -> beta (reuse s_dif) =================
    if (tid < 254) {
        float a = b6[0];
        #pragma unroll
        for (int c = 0; c < 20; ++c)
            a += w6[c] * bf2f(bufA[tid * X5S + c]);
        s_dif[tid] = 1.0f / (1.0f + __expf(-a)) + 0.1f;
    }
    __syncthreads();

    // ================= WENO5 =================
    const float eps = e_ptr[0];
    if (tid < TOUT) {
        int j = J0 + tid;
        if (j < n_out) {
            float a  = s_uu[tid + 5];
            float b  = s_uu[tid + 6];
            float c  = s_uu[tid + 7];
            float d  = s_uu[tid + 8];
            float ee = s_uu[tid + 9];
            float f  = s_uu[tid + 10];
            float m0 = s_dif[tid];
            float m1 = s_dif[tid + 1];
            float m2 = s_dif[tid + 2];

            const float i6 = 1.0f / 6.0f;
            float fp0 = (11.f * d - 7.f * ee + 2.f * f) * i6;
            float fp1 = (2.f * c + 5.f * d - ee) * i6;
            float fp2 = (-b + 5.f * c + 2.f * d) * i6;
            float fn0 = (11.f * c - 7.f * d + 2.f * ee) * i6;
            float fn1 = (2.f * b + 5.f * c - d) * i6;
            float fn2 = (-a + 5.f * b + 2.f * c) * i6;

            const float c1312 = 13.f / 12.f;
            float bp0 = c1312 * sq_f(d - 2.f * ee + f) + 0.25f * sq_f(3.f * d - 4.f * ee + f);
            float bp1 = c1312 * sq_f(c - 2.f * d + ee) + 0.25f * sq_f(c - ee);
            float bp2 = c1312 * sq_f(b - 2.f * c + d) + 0.25f * sq_f(b - 4.f * c + 3.f * d);
            float bn0 = c1312 * sq_f(c - 2.f * d + ee) + 0.25f * sq_f(3.f * c - 4.f * d + ee);
            float bn1 = c1312 * sq_f(b - 2.f * c + d) + 0.25f * sq_f(b - d);
            float bn2 = c1312 * sq_f(a - 2.f * b + c) + 0.25f * sq_f(a - 4.f * b + 3.f * c);

            bp0 *= m0; bp1 *= m1; bp2 *= m2;
            bn0 *= m0; bn1 *= m1; bn2 *= m2;

            float q0 = eps + bp0; q0 *= q0;
            float q1 = eps + bp1; q1 *= q1;
            float q2 = eps + bp2; q2 *= q2;
            float brs = bp2 - bp0; brs *= brs;
            float o0 = 0.1f * (1.f + brs / q0);
            float o1 = 0.6f * (1.f + brs / q1);
            float o2 = 0.3f * (1.f + brs / q2);
            float inv = 1.f / (o0 + o1 + o2);
            float fluxp = (o0 * fp0 + o1 * fp1 + o2 * fp2) * inv;

            q0 = eps + bn0; q0 *= q0;
            q1 = eps + bn1; q1 *= q1;
            q2 = eps + bn2; q2 *= q2;
            brs = bn2 - bn0; brs *= brs;
            o0 = 0.1f * (1.f + brs / q0);
            o1 = 0.6f * (1.f + brs / q1);
            o2 = 0.3f * (1.f + brs / q2);
            inv = 1.f / (o0 + o1 + o2);
            float fluxn = (o0 * fn0 + o1 * fn1 + o2 * fn2) * inv;

            out[j] = fluxp - fluxn;
        }
    }
}

extern "C" void kernel_launch(void* const* d_in, const int* in_sizes, int n_in,
                              void* d_out, int out_size, void* d_ws, size_t ws_size,
                              hipStream_t stream) {
    const float* uu = (const float*)d_in[0];
    const float* e  = (const float*)d_in[1];
    const float* w1 = (const float*)d_in[2];
    const float* b1 = (const float*)d_in[3];
    const float* w2 = (const float*)d_in[4];
    const float* b2 = (const float*)d_in[5];
    const float* w3 = (const float*)d_in[6];
    const float* b3 = (const float*)d_in[7];
    const float* w4 = (const float*)d_in[8];
    const float* b4 = (const float*)d_in[9];
    const float* w5 = (const float*)d_in[10];
    const float* b5 = (const float*)d_in[11];
    const float* w6 = (const float*)d_in[12];
    const float* b6 = (const float*)d_in[13];
    float* out = (float*)d_out;
    u16* wfr = (u16*)d_ws;
    const int N = in_sizes[0];
    const int nblocks = (out_size + TOUT - 1) / TOUT;

    build_frags_kernel<<<NFRAGS, 64, 0, stream>>>(w2, w3, w4, w5, wfr);
    weno_nn_kernel<<<nblocks, NTHREADS, 0, stream>>>(
        uu, e, w1, b1, b2, b3, b4, b5, w6, b6, wfr,
        out, out_size, N);
}

// Round 8
// 286.374 us; speedup vs baseline: 4.1366x; 1.1006x over previous
//
#include <hip/hip_runtime.h>
#include <math.h>

#define NTHREADS 512
#define TOUT 252            // outputs per block
#define NP 256              // x2/t3/x4 positions, base P0-1
#define X1ROWS 260          // x1 positions, base P0-3
#define X1S 40              // x1T row stride (ushorts): cols 0..19 data, 20..31 zero
#define X2S 40              // x2T stride: 40 real channels
#define T3S 80              // t3T stride: 80 real channels
#define X4S 40              // x4T stride: 40 real channels (rows 258)
#define X5S 26              // x5T stride: 20 real channels (26 = odd bank stride, conv6 conflict-free)
#define NDIF 264            // dif, base P0-5
#define NUU 266             // uu, base J0-4

// weight-fragment table in d_ws: 42 frags x 64 lanes x 8 bf16 (16 B)
#define F2_BASE 0           // conv2: 15 frags (mt 0..2, s 0..4)
#define F3_BASE 15          // conv3: 10 frags (mt 0..4, s 0..1)
#define F4_BASE 25          // conv4: 9  frags (mt 0..2, s 0..2)
#define F5_BASE 34          // conv5: 8  frags (mt 0..1, s 0..3)
#define NFRAGS 42

typedef unsigned short u16;
typedef unsigned int u32;
typedef __attribute__((ext_vector_type(8))) short bf16x8;   // 8 bf16 = 4 VGPR
typedef __attribute__((ext_vector_type(4))) float f32x4;    // MFMA acc

__device__ __forceinline__ float elu_f(float x) {
    return x > 0.0f ? x : (__expf(x) - 1.0f);
}
__device__ __forceinline__ float sq_f(float x) { return x * x; }
__device__ __forceinline__ u16 f2bf(float f) {              // RNE (setup kernel only)
    union { float f; u32 u; } v; v.f = f;
    u32 r = v.u + 0x7FFFu + ((v.u >> 16) & 1u);
    return (u16)(r >> 16);
}
__device__ __forceinline__ float bf2f(u16 h) {
    union { u32 u; float f; } v; v.u = ((u32)h) << 16;
    return v.f;
}
// pack two floats to bf16x2 by truncation: single v_perm_b32
__device__ __forceinline__ u32 pack_trunc(float a, float b) {
    union { float f; u32 u; } va, vb; va.f = a; vb.f = b;
#if __has_builtin(__builtin_amdgcn_perm)
    return __builtin_amdgcn_perm(vb.u, va.u, 0x07060302u);  // [a.b2,a.b3,b.b2,b.b3]
#else
    return (vb.u & 0xFFFF0000u) | (va.u >> 16);
#endif
}

// ---- setup kernel: build all MFMA A-operand weight frags once per launch ----
__global__ __launch_bounds__(64) void build_frags_kernel(
    const float* __restrict__ w2, const float* __restrict__ w3,
    const float* __restrict__ w4, const float* __restrict__ w5,
    u16* __restrict__ ws)
{
    const int f = blockIdx.x;      // 0..41
    const int lane = threadIdx.x;  // 0..63
    const int m = lane & 15;
    const int q = lane >> 4;
    float wvv[8];
    #pragma unroll
    for (int j = 0; j < 8; ++j) wvv[j] = 0.0f;

    if (f < F3_BASE) {                       // conv2: 20->40 k=5, K-dim = dk*32+ic
        int mt = (f - F2_BASE) / 5, s = (f - F2_BASE) % 5;
        int oc = mt * 16 + m;
        #pragma unroll
        for (int j = 0; j < 8; ++j) {
            int ic = q * 8 + j;
            if (oc < 40 && ic < 20) wvv[j] = w2[oc * 100 + ic * 5 + s];
        }
    } else if (f < F4_BASE) {                // conv3: 40->80 k=1, K=40 pad 64
        int mt = (f - F3_BASE) / 2, s = (f - F3_BASE) % 2;
        int oc = mt * 16 + m;
        #pragma unroll
        for (int j = 0; j < 8; ++j) {
            int k = s * 32 + q * 8 + j;
            if (k < 40) wvv[j] = w3[oc * 40 + k];
        }
    } else if (f < F5_BASE) {                // conv4: 80->40 k=1, K=80 pad 96
        int mt = (f - F4_BASE) / 3, s = (f - F4_BASE) % 3;
        int oc = mt * 16 + m;
        #pragma unroll
        for (int j = 0; j < 8; ++j) {
            int k = s * 32 + q * 8 + j;
            if (oc < 40 && k < 80) wvv[j] = w4[oc * 80 + k];
        }
    } else {                                 // conv5: 40->20 k=3, K=120: k=dk*40+ic
        int mt = (f - F5_BASE) / 4, s = (f - F5_BASE) % 4;
        int oc = mt * 16 + m;
        int k0 = s * 32 + q * 8;
        int dk = k0 / 40, ic0 = k0 - dk * 40;
        #pragma unroll
        for (int j = 0; j < 8; ++j) {
            if (oc < 20 && k0 < 120) wvv[j] = w5[oc * 120 + (ic0 + j) * 3 + dk];
        }
    }
    u32 pk[4];
    #pragma unroll
    for (int p = 0; p < 4; ++p)
        pk[p] = (u32)f2bf(wvv[2 * p]) | ((u32)f2bf(wvv[2 * p + 1]) << 16);
    u32* wp = (u32*)&ws[(f * 64 + lane) * 8];
    wp[0] = pk[0]; wp[1] = pk[1]; wp[2] = pk[2]; wp[3] = pk[3];
}

__device__ __forceinline__ bf16x8 ld_frag(const u16* ws, int f, int lane) {
    return *(const bf16x8*)&ws[(f * 64 + lane) * 8];
}

__global__ __launch_bounds__(NTHREADS, 1) void weno_nn_kernel(
    const float* __restrict__ uu, const float* __restrict__ e_ptr,
    const float* __restrict__ w1, const float* __restrict__ b1,
    const float* __restrict__ b2, const float* __restrict__ b3,
    const float* __restrict__ b4, const float* __restrict__ b5,
    const float* __restrict__ w6, const float* __restrict__ b6,
    const u16* __restrict__ wfr,
    float* __restrict__ out, int n_out, int N)
{
    __shared__ float s_uu[NUU];
    __shared__ float s_dif[NDIF];                       // reused as beta later
    __shared__ __align__(16) u16 bufA[NP * T3S];        // x1T(260x40) -> t3T(256x80) -> x5T(256x26)
    __shared__ __align__(16) u16 bufB[258 * X4S];       // x2T(256x40) -> x4T(258x40)

    const int tid  = threadIdx.x;
    const int lane = tid & 63;
    const int wv_id = __builtin_amdgcn_readfirstlane(tid >> 6);  // 0..7
    const int m    = lane & 15;         // M/N index within frag
    const int q    = lane >> 4;         // quad, 0..3
    const int J0   = blockIdx.x * TOUT;
    const int P0   = J0 + 2;
    const int U0   = J0 - 4;

    // ================= stage 0: uu tile =================
    for (int i = tid; i < NUU; i += NTHREADS) {
        int g = U0 + i;
        s_uu[i] = (g >= 0 && g < N) ? uu[g] : 0.0f;
    }
    __syncthreads();

    // ================= avg-diff =================
    for (int d = tid; d < NDIF; d += NTHREADS) {
        int g = P0 - 5 + d;
        float v = 0.0f;
        if (g >= 0 && g < N) {
            int j1 = g < N - 2 ? g : N - 2;
            int j0 = g - 1 > 0 ? g - 1 : 0;
            float dl = s_uu[j1 + 1 - U0] - s_uu[j1 - U0];
            float dr = s_uu[j0 + 1 - U0] - s_uu[j0 - U0];
            v = 0.5f * (dl + dr);
        }
        s_dif[d] = v;
    }
    __syncthreads();

    // ================= conv1: 1->20, k=5, elu -> x1T[pos][ic] =================
    for (int s = tid; s < X1ROWS; s += NTHREADS) {
        int g = P0 - 3 + s;
        bool valid = (g >= 0 && g < N);
        float dv[5];
        #pragma unroll
        for (int k = 0; k < 5; ++k) dv[k] = s_dif[s + k];
        float v[20];
        #pragma unroll
        for (int oc = 0; oc < 20; ++oc) {
            float a = b1[oc];
            #pragma unroll
            for (int k = 0; k < 5; ++k) a += w1[oc * 5 + k] * dv[k];
            v[oc] = valid ? elu_f(a) : 0.0f;
        }
        u32* rp = (u32*)&bufA[s * X1S];
        #pragma unroll
        for (int p = 0; p < 10; ++p)
            rp[p] = pack_trunc(v[2 * p], v[2 * p + 1]);
        #pragma unroll
        for (int p = 10; p < 16; ++p) rp[p] = 0;     // zero-pad ic 20..31
    }
    __syncthreads();

    // ================= conv2: 20->40, k=5 (im2col K=160) =================
    {
        bf16x8 a2[3][5];
        #pragma unroll
        for (int mt = 0; mt < 3; ++mt)
            #pragma unroll
            for (int s = 0; s < 5; ++s)
                a2[mt][s] = ld_frag(wfr, F2_BASE + mt * 5 + s, lane);
        f32x4 bias2[3];
        #pragma unroll
        for (int mt = 0; mt < 3; ++mt) {
            #pragma unroll
            for (int r = 0; r < 4; ++r) {
                int oc = mt * 16 + 4 * q + r;
                bias2[mt][r] = (oc < 40) ? b2[oc] : 0.0f;
            }
        }
        for (int t = 0; t < 2; ++t) {
            const int N0 = (wv_id * 2 + t) * 16;
            f32x4 acc[3];
            #pragma unroll
            for (int mt = 0; mt < 3; ++mt) acc[mt] = bias2[mt];   // bias seeded in acc
            #pragma unroll
            for (int s = 0; s < 5; ++s) {
                bf16x8 bfrag = *(const bf16x8*)&bufA[(N0 + m + s) * X1S + q * 8];
                #pragma unroll
                for (int mt = 0; mt < 3; ++mt)
                    acc[mt] = __builtin_amdgcn_mfma_f32_16x16x32_bf16(a2[mt][s], bfrag, acc[mt], 0, 0, 0);
            }
            #pragma unroll
            for (int mt = 0; mt < 3; ++mt) {
                int oc0 = mt * 16 + 4 * q;
                if (oc0 < 40) {
                    u32* wp = (u32*)&bufB[(N0 + m) * X2S + oc0];
                    wp[0] = pack_trunc(elu_f(acc[mt][0]), elu_f(acc[mt][1]));
                    wp[1] = pack_trunc(elu_f(acc[mt][2]), elu_f(acc[mt][3]));
                }
            }
        }
    }
    __syncthreads();

    // ================= conv3: 40->80, k=1 (K=40 pad 64) =================
    {
        bf16x8 a3[5][2];
        #pragma unroll
        for (int mt = 0; mt < 5; ++mt)
            #pragma unroll
            for (int s = 0; s < 2; ++s)
                a3[mt][s] = ld_frag(wfr, F3_BASE + mt * 2 + s, lane);
        f32x4 bias3[5];
        #pragma unroll
        for (int mt = 0; mt < 5; ++mt) {
            #pragma unroll
            for (int r = 0; r < 4; ++r) bias3[mt][r] = b3[mt * 16 + 4 * q + r];
        }
        for (int t = 0; t < 2; ++t) {
            const int N0 = (wv_id * 2 + t) * 16;
            f32x4 acc[5];
            #pragma unroll
            for (int mt = 0; mt < 5; ++mt) acc[mt] = bias3[mt];
            // s=0: k 0..31
            {
                bf16x8 bfrag = *(const bf16x8*)&bufB[(N0 + m) * X2S + q * 8];
                #pragma unroll
                for (int mt = 0; mt < 5; ++mt)
                    acc[mt] = __builtin_amdgcn_mfma_f32_16x16x32_bf16(a3[mt][0], bfrag, acc[mt], 0, 0, 0);
            }
            // s=1: only q==0 has valid k (32..39); other quads multiply zero A-weights
            {
                bf16x8 bfrag = *(const bf16x8*)&bufB[(N0 + m) * X2S + ((q == 0) ? 32 : 0)];
                #pragma unroll
                for (int mt = 0; mt < 5; ++mt)
                    acc[mt] = __builtin_amdgcn_mfma_f32_16x16x32_bf16(a3[mt][1], bfrag, acc[mt], 0, 0, 0);
            }
            #pragma unroll
            for (int mt = 0; mt < 5; ++mt) {
                int oc0 = mt * 16 + 4 * q;
                u32* wp = (u32*)&bufA[(N0 + m) * T3S + oc0];
                wp[0] = pack_trunc(elu_f(acc[mt][0]), elu_f(acc[mt][1]));
                wp[1] = pack_trunc(elu_f(acc[mt][2]), elu_f(acc[mt][3]));
            }
        }
    }
    __syncthreads();

    // ================= conv4: 80->40, k=1 (K=80 pad 96) =================
    {
        bf16x8 a4[3][3];
        #pragma unroll
        for (int mt = 0; mt < 3; ++mt)
            #pragma unroll
            for (int s = 0; s < 3; ++s)
                a4[mt][s] = ld_frag(wfr, F4_BASE + mt * 3 + s, lane);
        f32x4 bias4[3];
        #pragma unroll
        for (int mt = 0; mt < 3; ++mt) {
            #pragma unroll
            for (int r = 0; r < 4; ++r) {
                int oc = mt * 16 + 4 * q + r;
                bias4[mt][r] = (oc < 40) ? b4[oc] : 0.0f;
            }
        }
        // zero-pad x4T rows 256,257 (read by conv5 at right edge of tile)
        if (tid < 80) bufB[256 * X4S + tid] = 0;
        for (int t = 0; t < 2; ++t) {
            const int N0 = (wv_id * 2 + t) * 16;
            f32x4 acc[3];
            #pragma unroll
            for (int mt = 0; mt < 3; ++mt) acc[mt] = bias4[mt];
            #pragma unroll
            for (int s = 0; s < 3; ++s) {
                int k0 = s * 32 + q * 8;
                // k0 >= 80 lanes have zero A-weights; clamp address
                bf16x8 bfrag = *(const bf16x8*)&bufA[(N0 + m) * T3S + ((k0 < 80) ? k0 : 0)];
                #pragma unroll
                for (int mt = 0; mt < 3; ++mt)
                    acc[mt] = __builtin_amdgcn_mfma_f32_16x16x32_bf16(a4[mt][s], bfrag, acc[mt], 0, 0, 0);
            }
            #pragma unroll
            for (int mt = 0; mt < 3; ++mt) {
                int oc0 = mt * 16 + 4 * q;
                if (oc0 < 40) {
                    u32* wp = (u32*)&bufB[(N0 + m) * X4S + oc0];
                    wp[0] = pack_trunc(elu_f(acc[mt][0]), elu_f(acc[mt][1]));
                    wp[1] = pack_trunc(elu_f(acc[mt][2]), elu_f(acc[mt][3]));
                }
            }
        }
    }
    __syncthreads();

    // ================= conv5: 40->20, k=3 (im2col K=120) =================
    {
        bf16x8 a5[2][4];
        #pragma unroll
        for (int mt = 0; mt < 2; ++mt)
            #pragma unroll
            for (int s = 0; s < 4; ++s)
                a5[mt][s] = ld_frag(wfr, F5_BASE + mt * 4 + s, lane);
        f32x4 bias5[2];
        #pragma unroll
        for (int mt = 0; mt < 2; ++mt) {
            #pragma unroll
            for (int r = 0; r < 4; ++r) {
                int oc = mt * 16 + 4 * q + r;
                bias5[mt][r] = (oc < 20) ? b5[oc] : 0.0f;
            }
        }
        for (int t = 0; t < 2; ++t) {
            const int N0 = (wv_id * 2 + t) * 16;
            f32x4 acc[2];
            #pragma unroll
            for (int mt = 0; mt < 2; ++mt) acc[mt] = bias5[mt];
            #pragma unroll
            for (int s = 0; s < 4; ++s) {
                int k0 = s * 32 + q * 8;
                int dk = (k0 < 120) ? (k0 / 40) : 0;
                int ic0 = (k0 < 120) ? (k0 - dk * 40) : 0;
                bf16x8 bfrag = *(const bf16x8*)&bufB[(N0 + m + dk) * X4S + ic0];
                #pragma unroll
                for (int mt = 0; mt < 2; ++mt)
                    acc[mt] = __builtin_amdgcn_mfma_f32_16x16x32_bf16(a5[mt][s], bfrag, acc[mt], 0, 0, 0);
            }
            #pragma unroll
            for (int mt = 0; mt < 2; ++mt) {
                int oc0 = mt * 16 + 4 * q;
                if (oc0 < 20) {
                    u32* wp = (u32*)&bufA[(N0 + m) * X5S + oc0];
                    wp[0] = pack_trunc(elu_f(acc[mt][0]), elu_f(acc[mt][1]));
                    wp[1] = pack_trunc(elu_f(acc[mt][2]), elu_f(acc[mt][3]));
                }
            }
        }
    }
    __syncthreads();

    // ================= conv6: 20->1, sigmoid + 0.1 -> beta (reuse s_dif) =================
    if (tid < 254) {
        float a = b6[0];
        #pragma unroll
        for (int c = 0; c < 20; ++c)
            a += w6[c] * bf2f(bufA[tid * X5S + c]);
        s_dif[tid] = 1.0f / (1.0f + __expf(-a)) + 0.1f;
    }
    __syncthreads();

    // ================= WENO5 =================
    const float eps = e_ptr[0];
    if (tid < TOUT) {
        int j = J0 + tid;
        if (j < n_out) {
            float a  = s_uu[tid + 5];
            float b  = s_uu[tid + 6];
            float c  = s_uu[tid + 7];
            float d  = s_uu[tid + 8];
            float ee = s_uu[tid + 9];
            float f  = s_uu[tid + 10];
            float m0 = s_dif[tid];
            float m1 = s_dif[tid + 1];
            float m2 = s_dif[tid + 2];

            const float i6 = 1.0f / 6.0f;
            float fp0 = (11.f * d - 7.f * ee + 2.f * f) * i6;
            float fp1 = (2.f * c + 5.f * d - ee) * i6;
            float fp2 = (-b + 5.f * c + 2.f * d) * i6;
            float fn0 = (11.f * c - 7.f * d + 2.f * ee) * i6;
            float fn1 = (2.f * b + 5.f * c - d) * i6;
            float fn2 = (-a + 5.f * b + 2.f * c) * i6;

            const float c1312 = 13.f / 12.f;
            float bp0 = c1312 * sq_f(d - 2.f * ee + f) + 0.25f * sq_f(3.f * d - 4.f * ee + f);
            float bp1 = c1312 * sq_f(c - 2.f * d + ee) + 0.25f * sq_f(c - ee);
            float bp2 = c1312 * sq_f(b - 2.f * c + d) + 0.25f * sq_f(b - 4.f * c + 3.f * d);
            float bn0 = c1312 * sq_f(c - 2.f * d + ee) + 0.25f * sq_f(3.f * c - 4.f * d + ee);
            float bn1 = c1312 * sq_f(b - 2.f * c + d) + 0.25f * sq_f(b - d);
            float bn2 = c1312 * sq_f(a - 2.f * b + c) + 0.25f * sq_f(a - 4.f * b + 3.f * c);

            bp0 *= m0; bp1 *= m1; bp2 *= m2;
            bn0 *= m0; bn1 *= m1; bn2 *= m2;

            float q0 = eps + bp0; q0 *= q0;
            float q1 = eps + bp1; q1 *= q1;
            float q2 = eps + bp2; q2 *= q2;
            float brs = bp2 - bp0; brs *= brs;
            float o0 = 0.1f * (1.f + brs / q0);
            float o1 = 0.6f * (1.f + brs / q1);
            float o2 = 0.3f * (1.f + brs / q2);
            float inv = 1.f / (o0 + o1 + o2);
            float fluxp = (o0 * fp0 + o1 * fp1 + o2 * fp2) * inv;

            q0 = eps + bn0; q0 *= q0;
            q1 = eps + bn1; q1 *= q1;
            q2 = eps + bn2; q2 *= q2;
            brs = bn2 - bn0; brs *= brs;
            o0 = 0.1f * (1.f + brs / q0);
            o1 = 0.6f * (1.f + brs / q1);
            o2 = 0.3f * (1.f + brs / q2);
            inv = 1.f / (o0 + o1 + o2);
            float fluxn = (o0 * fn0 + o1 * fn1 + o2 * fn2) * inv;

            out[j] = fluxp - fluxn;
        }
    }
}

extern "C" void kernel_launch(void* const* d_in, const int* in_sizes, int n_in,
                              void* d_out, int out_size, void* d_ws, size_t ws_size,
                              hipStream_t stream) {
    const float* uu = (const float*)d_in[0];
    const float* e  = (const float*)d_in[1];
    const float* w1 = (const float*)d_in[2];
    const float* b1 = (const float*)d_in[3];
    const float* w2 = (const float*)d_in[4];
    const float* b2 = (const float*)d_in[5];
    const float* w3 = (const float*)d_in[6];
    const float* b3 = (const float*)d_in[7];
    const float* w4 = (const float*)d_in[8];
    const float* b4 = (const float*)d_in[9];
    const float* w5 = (const float*)d_in[10];
    const float* b5 = (const float*)d_in[11];
    const float* w6 = (const float*)d_in[12];
    const float* b6 = (const float*)d_in[13];
    float* out = (float*)d_out;
    u16* wfr = (u16*)d_ws;
    const int N = in_sizes[0];
    const int nblocks = (out_size + TOUT - 1) / TOUT;

    build_frags_kernel<<<NFRAGS, 64, 0, stream>>>(w2, w3, w4, w5, wfr);
    weno_nn_kernel<<<nblocks, NTHREADS, 0, stream>>>(
        uu, e, w1, b1, b2, b3, b4, b5, w6, b6, wfr,
        out, out_size, N);
}